// Round 1
// baseline (376.723 us; speedup 1.0000x reference)
//
#include <hip/hip_runtime.h>
#include <hip/hip_bf16.h>
#include <math.h>

// ---------------- workspace layout (floats) ----------------
#define WS_AT    0            // 320*64 = 20480
#define WS_YSUM  20480        // 40
#define WS_XMAX  20544        // 8 (as uint bits)
#define WS_HIST  20552        // 8*102 int
#define WS_THR   21376        // 8*4
#define WS_XP    21504        // 8*3*256*256 = 1572864
#define WS_IA    1594368      // 8*256*256   = 524288
#define WS_XGL   2118656      // 8*256*256   = 524288
// total ~2.64M floats = 10.6 MB

#define GDM_OUT  655360       // 8*5*128*128

static __device__ __forceinline__ float xv_val(int i) {
    double t = (double)i / 100.0;
    return (float)(10.0 * t * t * t);
}

// ---- G1: avgpool 3x3 s2 p1 on x[8,3,512,512] -> xp[8,3,256,256], ia = channel mean ----
__global__ __launch_bounds__(256) void k_pool3_mean(const float* __restrict__ x,
                                                    float* __restrict__ xp,
                                                    float* __restrict__ ia) {
    int idx = blockIdx.x * 256 + threadIdx.x;
    if (idx >= 8 * 256 * 256) return;
    int b = idx >> 16; int p = idx & 65535; int oy = p >> 8; int ox = p & 255;
    float cs[3];
#pragma unroll
    for (int c = 0; c < 3; ++c) {
        const float* src = x + (((size_t)(b * 3 + c)) << 18);
        float s = 0.f;
#pragma unroll
        for (int dy = -1; dy <= 1; ++dy) {
            int iy = 2 * oy + dy; if ((unsigned)iy >= 512u) continue;
#pragma unroll
            for (int dx = -1; dx <= 1; ++dx) {
                int ix = 2 * ox + dx; if ((unsigned)ix >= 512u) continue;
                s += src[iy * 512 + ix];
            }
        }
        cs[c] = s * (1.f / 9.f);
        xp[(((size_t)(b * 3 + c)) << 16) + p] = cs[c];
    }
    ia[(((size_t)b) << 16) + p] = (cs[0] + cs[1] + cs[2]) * (1.f / 3.f);
}

// ---- G2: conv7x7 s2 p3 on xp -> spatial sums per (b,co) ----
__global__ __launch_bounds__(256) void k_conv7_reduce(const float* __restrict__ xp,
                                                      const float* __restrict__ w,
                                                      float* __restrict__ ysum) {
    int co = blockIdx.y, b = blockIdx.z;
    int p = blockIdx.x * 256 + threadIdx.x;
    int oy = p >> 7, ox = p & 127;
    __shared__ float wsm[147];
    if (threadIdx.x < 147) wsm[threadIdx.x] = w[co * 147 + threadIdx.x];
    __syncthreads();
    float s = 0.f;
    for (int ic = 0; ic < 3; ++ic) {
        const float* src = xp + (((size_t)(b * 3 + ic)) << 16);
#pragma unroll
        for (int r = 0; r < 7; ++r) {
            int iy = 2 * oy - 3 + r; if ((unsigned)iy >= 256u) continue;
#pragma unroll
            for (int ss = 0; ss < 7; ++ss) {
                int ix = 2 * ox - 3 + ss; if ((unsigned)ix >= 256u) continue;
                s += wsm[(ic * 7 + r) * 7 + ss] * src[iy * 256 + ix];
            }
        }
    }
    __shared__ float red[256];
    red[threadIdx.x] = s; __syncthreads();
    for (int off = 128; off > 0; off >>= 1) {
        if (threadIdx.x < off) red[threadIdx.x] += red[threadIdx.x + off];
        __syncthreads();
    }
    if (threadIdx.x == 0) atomicAdd(&ysum[b * 5 + co], red[0]);
}

// ---- G4: x_GL = |conv5x5(ia, a1*GL)| threshold, histogram + per-b max ----
__global__ __launch_bounds__(256) void k_gl_hist(const float* __restrict__ ia,
                                                 const float* __restrict__ gdmw,
                                                 float* __restrict__ xgl,
                                                 int* __restrict__ hist,
                                                 unsigned* __restrict__ xmax) {
    int b = blockIdx.y;
    int p = blockIdx.x * 256 + threadIdx.x;
    int y = p >> 8, x = p & 255;
    __shared__ float xv[101];
    __shared__ int sh[102];
    __shared__ float redm[256];
    if (threadIdx.x < 101) xv[threadIdx.x] = xv_val(threadIdx.x);
    if (threadIdx.x < 102) sh[threadIdx.x] = 0;
    __syncthreads();
    const float* src = ia + (((size_t)b) << 16);
    float a1 = gdmw[0] * 4.f;
    auto rd = [&](int dy, int dx) -> float {
        int iy = y + dy, ix = x + dx;
        if ((unsigned)iy >= 256u || (unsigned)ix >= 256u) return 0.f;
        return src[iy * 256 + ix];
    };
    float acc = rd(0, 0)
        - 0.125f  * (rd(-1, 0) + rd(0, -1) + rd(0, 1) + rd(1, 0))
        - 0.0625f * (rd(-2, 0) + rd(-1, -1) + rd(-1, 1) + rd(0, -2) +
                     rd(0, 2) + rd(1, -1) + rd(1, 1) + rd(2, 0));
    float raw = fabsf(a1 * acc);
    float val = (raw < 1e-6f) ? 0.f : raw;
    xgl[(((size_t)b) << 16) + p] = val;
    if (val > 0.f) {
        int lo = 0, hi = 101;
        while (lo < hi) { int mid = (lo + hi) >> 1; if (val <= xv[mid]) hi = mid; else lo = mid + 1; }
        atomicAdd(&sh[lo], 1);
    }
    redm[threadIdx.x] = val; __syncthreads();
    for (int off = 128; off > 0; off >>= 1) {
        if (threadIdx.x < off) redm[threadIdx.x] = fmaxf(redm[threadIdx.x], redm[threadIdx.x + off]);
        __syncthreads();
    }
    if (threadIdx.x == 0) atomicMax(&xmax[b], __float_as_uint(redm[0]));
    if (threadIdx.x < 102 && sh[threadIdx.x]) atomicAdd(&hist[b * 102 + threadIdx.x], sh[threadIdx.x]);
}

// ---- G5: weight_att (BN affine on mean), sort params, argmin over cumulative pct ----
__global__ void k_thresholds(const float* __restrict__ ysum, const float* __restrict__ gamma,
                             const float* __restrict__ beta, const float* __restrict__ mean,
                             const float* __restrict__ var, const int* __restrict__ hist,
                             float* __restrict__ thr) {
    int b = threadIdx.x;
    if (b >= 8) return;
    float wa[5];
    for (int c = 1; c < 5; ++c) {
        float m = ysum[b * 5 + c] * (1.f / 16384.f);
        wa[c] = tanhf((m - mean[c]) * rsqrtf(var[c] + 1e-5f) * gamma[c] + beta[c]);
    }
    float pr[4] = {0.2f + 0.05f * wa[1], 0.4f + 0.05f * wa[2],
                   0.6f + 0.05f * wa[3], 0.8f + 0.05f * wa[4]};
    auto sw = [&](int i, int j) { if (pr[i] > pr[j]) { float t = pr[i]; pr[i] = pr[j]; pr[j] = t; } };
    sw(0, 1); sw(2, 3); sw(0, 2); sw(1, 3); sw(1, 2);
    int all = 0;
    for (int i = 0; i <= 101; ++i) all += hist[b * 102 + i];
    float bestz[4] = {1e30f, 1e30f, 1e30f, 1e30f};
    int besti[4] = {0, 0, 0, 0};
    int cum = 0;
    for (int i = 0; i <= 100; ++i) {
        cum += hist[b * 102 + i];
        float pct = (float)cum / (float)all;
        for (int t = 0; t < 4; ++t) {
            float z = fabsf(pct - pr[t]);
            if (z < bestz[t]) { bestz[t] = z; besti[t] = i; }
        }
    }
    for (int t = 0; t < 4; ++t) thr[b * 4 + t] = xv_val(besti[t]);
}

// ---- G6: banded mask -> m0 [8,5,256,256] ----
__global__ __launch_bounds__(256) void k_mask(const float* __restrict__ xgl,
                                              const float* __restrict__ thr,
                                              const unsigned* __restrict__ xmax,
                                              float* __restrict__ m) {
    int idx = blockIdx.x * 256 + threadIdx.x;
    int p = idx & 65535; int bc = idx >> 16; int band = bc % 5; int b = bc / 5;
    float v = xgl[(((size_t)b) << 16) + p];
    float tmin = (band == 0) ? 0.f : thr[b * 4 + band - 1];
    float tmax = (band == 4) ? __uint_as_float(xmax[b]) : thr[b * 4 + band];
    m[idx] = (v > tmin && v <= tmax) ? 1.f : 0.f;
}

// ---- separable 9-tap box passes ----
__global__ __launch_bounds__(256) void k_box9_h(const float* __restrict__ in, float* __restrict__ out) {
    int idx = blockIdx.x * 256 + threadIdx.x;        // 40*256*256
    int plane = idx >> 16; int p = idx & 65535; int y = p >> 8, x = p & 255;
    const float* r = in + (((size_t)plane) << 16) + y * 256;
    float s = 0.f;
#pragma unroll
    for (int d = -4; d <= 4; ++d) { int ix = x + d; if ((unsigned)ix < 256u) s += r[ix]; }
    out[idx] = s * (1.f / 9.f);
}
__global__ __launch_bounds__(256) void k_box9_v(const float* __restrict__ in, float* __restrict__ out) {
    int idx = blockIdx.x * 256 + threadIdx.x;
    int plane = idx >> 16; int p = idx & 65535; int y = p >> 8, x = p & 255;
    const float* base = in + (((size_t)plane) << 16);
    float s = 0.f;
#pragma unroll
    for (int d = -4; d <= 4; ++d) { int iy = y + d; if ((unsigned)iy < 256u) s += base[iy * 256 + x]; }
    out[idx] = s * (1.f / 9.f);
}
__global__ __launch_bounds__(256) void k_box9_h_s2(const float* __restrict__ in, float* __restrict__ out) {
    int idx = blockIdx.x * 256 + threadIdx.x;        // 40*256*128
    int plane = idx >> 15; int p = idx & 32767; int y = p >> 7, ox = p & 127;
    const float* r = in + (((size_t)plane) << 16) + y * 256;
    float s = 0.f;
#pragma unroll
    for (int d = -4; d <= 4; ++d) { int ix = 2 * ox + d; if ((unsigned)ix < 256u) s += r[ix]; }
    out[idx] = s * (1.f / 9.f);
}
__global__ __launch_bounds__(256) void k_box9_v_s2(const float* __restrict__ in, float* __restrict__ out) {
    int idx = blockIdx.x * 256 + threadIdx.x;        // 40*128*128
    int plane = idx >> 14; int p = idx & 16383; int oy = p >> 7, ox = p & 127;
    const float* base = in + (((size_t)plane) << 15);
    float s = 0.f;
#pragma unroll
    for (int d = -4; d <= 4; ++d) { int iy = 2 * oy + d; if ((unsigned)iy < 256u) s += base[iy * 128 + ox]; }
    out[idx] = s * (1.f / 9.f);
}

// ---- G12: per-(b,band) min-max normalize -> gdm_out ----
__global__ __launch_bounds__(256) void k_norm(const float* __restrict__ in, float* __restrict__ out) {
    int plane = blockIdx.x; // 40
    const float* src = in + (size_t)plane * 16384;
    float mn = 1e30f, mx = -1e30f;
    for (int i = threadIdx.x; i < 16384; i += 256) {
        float v = src[i]; mn = fminf(mn, v); mx = fmaxf(mx, v);
    }
    __shared__ float smn[256], smx[256];
    smn[threadIdx.x] = mn; smx[threadIdx.x] = mx; __syncthreads();
    for (int off = 128; off > 0; off >>= 1) {
        if (threadIdx.x < off) {
            smn[threadIdx.x] = fminf(smn[threadIdx.x], smn[threadIdx.x + off]);
            smx[threadIdx.x] = fmaxf(smx[threadIdx.x], smx[threadIdx.x + off]);
        }
        __syncthreads();
    }
    float lo = smn[0], range = smx[0] - smn[0];
    for (int i = threadIdx.x; i < 16384; i += 256) {
        out[(size_t)plane * 16384 + i] = (src[i] - lo) / range;
    }
}

// ---- H1: A_d[o][c] = sum_m fc_w[o][d*64+m] * g_d[m][c]; stored as At[(d*64+c)*64+o] ----
__global__ __launch_bounds__(256) void k_mixA(const float* __restrict__ hw,
                                              const float* __restrict__ fcw,
                                              float* __restrict__ At) {
    int idx = blockIdx.x * 256 + threadIdx.x;  // 320*64
    int o = idx & 63; int k = idx >> 6;
    int d = k >> 6; int c = k & 63;
    const int goff[5] = {0, 1, 2, 3, 8};
    float scale = (d == 4) ? 4.f : 1.f;
    int off = goff[d];
    float s = 0.f;
    for (int m = 0; m < 64; ++m)
        s += fcw[o * 320 + d * 64 + m] * hw[(m * 64 + c) * 9 + off];
    At[k * 64 + o] = s * scale;
}

// ---- H2: fused depthwise stencils + channel-mix GEMM ----
__global__ __launch_bounds__(256) void k_hge(const float* __restrict__ feat,
                                             const float* __restrict__ At,
                                             const float* __restrict__ fcb,
                                             float* __restrict__ out) {
    int tile = blockIdx.x; int b = blockIdx.y;
    int ty = (tile >> 3) * 16, tx = (tile & 7) * 16;
    __shared__ float ft[20][21];
    __shared__ float tl[5][256];
    __shared__ float al[320];
    int tid = threadIdx.x;
    int og = tid >> 5, pg = tid & 31;
    float acc[8][8];
#pragma unroll
    for (int i = 0; i < 8; ++i)
#pragma unroll
        for (int j = 0; j < 8; ++j) acc[i][j] = 0.f;
    int py = tid >> 4, px = tid & 15;

    for (int c = 0; c < 64; ++c) {
        __syncthreads();
        const float* src = feat + (((size_t)(b * 64 + c)) << 14);
        for (int l = tid; l < 400; l += 256) {
            int fy = l / 20, fx = l - fy * 20;
            int gy = ty - 2 + fy, gx = tx - 2 + fx;
            ft[fy][fx] = ((unsigned)gy < 128u && (unsigned)gx < 128u) ? src[gy * 128 + gx] : 0.f;
        }
        for (int l = tid; l < 320; l += 256)
            al[l] = At[(((l >> 6) * 64 + c) << 6) + (l & 63)];
        __syncthreads();
        {
            int cy = py + 2, cx = px + 2;
            float fm2 = ft[cy - 2][cx], f2p = ft[cy + 2][cx];
            float fl2 = ft[cy][cx - 2], fr2 = ft[cy][cx + 2];
            float a  = ft[cy - 1][cx - 1], bq = ft[cy - 1][cx], cc = ft[cy - 1][cx + 1];
            float dd = ft[cy][cx - 1],     ee = ft[cy][cx],     ffv = ft[cy][cx + 1];
            float g  = ft[cy + 1][cx - 1], h  = ft[cy + 1][cx], i2 = ft[cy + 1][cx + 1];
            tl[0][tid] = (a + 2.f * bq + cc) - (g + 2.f * h + i2);
            tl[1][tid] = 2.f * a + bq + dd - ffv - h - 2.f * i2;
            tl[2][tid] = (a - cc) + 2.f * (dd - ffv) + (g - i2);
            tl[3][tid] = -bq - 2.f * cc + dd - ffv + 2.f * g + h;
            tl[4][tid] = ee - 0.125f * (bq + dd + ffv + h)
                       - 0.0625f * (fm2 + a + cc + fl2 + fr2 + g + i2 + f2p);
        }
        __syncthreads();
#pragma unroll
        for (int d = 0; d < 5; ++d) {
            float av[8];
#pragma unroll
            for (int oi = 0; oi < 8; ++oi) av[oi] = al[d * 64 + og * 8 + oi];
#pragma unroll
            for (int pj = 0; pj < 8; ++pj) {
                float tv = tl[d][pg + 32 * pj];
#pragma unroll
                for (int oi = 0; oi < 8; ++oi) acc[pj][oi] = fmaf(av[oi], tv, acc[pj][oi]);
            }
        }
    }
#pragma unroll
    for (int oi = 0; oi < 8; ++oi) {
        int o = og * 8 + oi;
        float bias = fcb[o];
#pragma unroll
        for (int pj = 0; pj < 8; ++pj) {
            int p = pg + 32 * pj;
            int yy = ty + (p >> 4), xx = tx + (p & 15);
            out[(((size_t)(b * 64 + o)) << 14) + yy * 128 + xx] = acc[pj][oi] + bias;
        }
    }
}

extern "C" void kernel_launch(void* const* d_in, const int* in_sizes, int n_in,
                              void* d_out, int out_size, void* d_ws, size_t ws_size,
                              hipStream_t stream) {
    const float* x    = (const float*)d_in[0];
    const float* gdmw = (const float*)d_in[1];
    const float* convw= (const float*)d_in[2];
    const float* bng  = (const float*)d_in[3];
    const float* bnb  = (const float*)d_in[4];
    const float* bnm  = (const float*)d_in[5];
    const float* bnv  = (const float*)d_in[6];
    const float* feat = (const float*)d_in[7];
    const float* hw   = (const float*)d_in[8];
    const float* fcw  = (const float*)d_in[9];
    const float* fcb  = (const float*)d_in[10];
    float* out = (float*)d_out;
    float* ws  = (float*)d_ws;

    float* At   = ws + WS_AT;
    float* ysum = ws + WS_YSUM;
    unsigned* xmax = (unsigned*)(ws + WS_XMAX);
    int* hist   = (int*)(ws + WS_HIST);
    float* thr  = ws + WS_THR;
    float* xp   = ws + WS_XP;
    float* ia   = ws + WS_IA;
    float* xgl  = ws + WS_XGL;

    // pool ping-pong buffers live in the hge half of d_out (written last)
    float* hge = out + GDM_OUT;
    float* m0  = hge;                 // 2621440
    float* m1  = hge + 2621440;       // 2621440
    float* ts  = hge + 5242880;       // 1310720   (all < 8388608)

    hipMemsetAsync(ws + WS_YSUM, 0, (WS_XP - WS_YSUM) * sizeof(float), stream);

    k_pool3_mean  <<<2048, 256, 0, stream>>>(x, xp, ia);
    k_conv7_reduce<<<dim3(64, 5, 8), 256, 0, stream>>>(xp, convw, ysum);
    k_gl_hist     <<<dim3(256, 8), 256, 0, stream>>>(ia, gdmw, xgl, hist, xmax);
    k_thresholds  <<<1, 64, 0, stream>>>(ysum, bng, bnb, bnm, bnv, hist, thr);
    k_mask        <<<10240, 256, 0, stream>>>(xgl, thr, xmax, m0);
    k_box9_h      <<<10240, 256, 0, stream>>>(m0, m1);
    k_box9_v      <<<10240, 256, 0, stream>>>(m1, m0);
    k_box9_h      <<<10240, 256, 0, stream>>>(m0, m1);
    k_box9_v      <<<10240, 256, 0, stream>>>(m1, m0);
    k_box9_h_s2   <<<5120, 256, 0, stream>>>(m0, ts);
    k_box9_v_s2   <<<2560, 256, 0, stream>>>(ts, m1);
    k_norm        <<<40, 256, 0, stream>>>(m1, out);

    k_mixA        <<<80, 256, 0, stream>>>(hw, fcw, At);
    k_hge         <<<dim3(64, 8), 256, 0, stream>>>(feat, At, fcb, out + GDM_OUT);
}

// Round 2
// 277.283 us; speedup vs baseline: 1.3586x; 1.3586x over previous
//
#include <hip/hip_runtime.h>
#include <hip/hip_bf16.h>
#include <math.h>

// ---------------- workspace layout (floats) ----------------
#define WS_AT    0            // 320*64 = 20480
#define WS_YSUM  20480        // 40
#define WS_XMAX  20520        // 8
#define WS_HIST  20528        // 8*102 int = 816
#define WS_THR   21344        // 32
#define WS_MN    21376        // 40 (uint)
#define WS_MX    21440        // 40 (uint)
#define WS_XP    21504        // 8*3*256*256 = 1572864
#define WS_IA    1594368      // 8*256*256   = 524288
#define WS_XGL   2118656      // 8*256*256   = 524288
// total ~2.64M floats = 10.6 MB (same footprint as round 1)

#define GDM_OUT  655360       // 8*5*128*128

static __device__ __forceinline__ float xv_val(int i) {
    double t = (double)i / 100.0;
    return (float)(10.0 * t * t * t);
}

// ---- G1: avgpool 3x3 s2 p1 on x[8,3,512,512] -> xp[8,3,256,256], ia = channel mean ----
__global__ __launch_bounds__(256) void k_pool3_mean(const float* __restrict__ x,
                                                    float* __restrict__ xp,
                                                    float* __restrict__ ia) {
    int idx = blockIdx.x * 256 + threadIdx.x;
    if (idx >= 8 * 256 * 256) return;
    int b = idx >> 16; int p = idx & 65535; int oy = p >> 8; int ox = p & 255;
    float cs[3];
#pragma unroll
    for (int c = 0; c < 3; ++c) {
        const float* src = x + (((size_t)(b * 3 + c)) << 18);
        float s = 0.f;
#pragma unroll
        for (int dy = -1; dy <= 1; ++dy) {
            int iy = 2 * oy + dy; if ((unsigned)iy >= 512u) continue;
#pragma unroll
            for (int dx = -1; dx <= 1; ++dx) {
                int ix = 2 * ox + dx; if ((unsigned)ix >= 512u) continue;
                s += src[iy * 512 + ix];
            }
        }
        cs[c] = s * (1.f / 9.f);
        xp[(((size_t)(b * 3 + c)) << 16) + p] = cs[c];
    }
    ia[(((size_t)b) << 16) + p] = (cs[0] + cs[1] + cs[2]) * (1.f / 3.f);
}

// ---- G2: conv7x7 s2 p3 on xp -> spatial sums per (b,co) ----
__global__ __launch_bounds__(256) void k_conv7_reduce(const float* __restrict__ xp,
                                                      const float* __restrict__ w,
                                                      float* __restrict__ ysum) {
    int co = blockIdx.y, b = blockIdx.z;
    int p = blockIdx.x * 256 + threadIdx.x;
    int oy = p >> 7, ox = p & 127;
    __shared__ float wsm[147];
    if (threadIdx.x < 147) wsm[threadIdx.x] = w[co * 147 + threadIdx.x];
    __syncthreads();
    float s = 0.f;
    for (int ic = 0; ic < 3; ++ic) {
        const float* src = xp + (((size_t)(b * 3 + ic)) << 16);
#pragma unroll
        for (int r = 0; r < 7; ++r) {
            int iy = 2 * oy - 3 + r; if ((unsigned)iy >= 256u) continue;
#pragma unroll
            for (int ss = 0; ss < 7; ++ss) {
                int ix = 2 * ox - 3 + ss; if ((unsigned)ix >= 256u) continue;
                s += wsm[(ic * 7 + r) * 7 + ss] * src[iy * 256 + ix];
            }
        }
    }
    __shared__ float red[256];
    red[threadIdx.x] = s; __syncthreads();
    for (int off = 128; off > 0; off >>= 1) {
        if (threadIdx.x < off) red[threadIdx.x] += red[threadIdx.x + off];
        __syncthreads();
    }
    if (threadIdx.x == 0) atomicAdd(&ysum[b * 5 + co], red[0]);
}

// ---- G4: x_GL = |conv5x5(ia, a1*GL)| threshold, histogram + per-b max ----
__global__ __launch_bounds__(256) void k_gl_hist(const float* __restrict__ ia,
                                                 const float* __restrict__ gdmw,
                                                 float* __restrict__ xgl,
                                                 int* __restrict__ hist,
                                                 unsigned* __restrict__ xmax) {
    int b = blockIdx.y;
    int p = blockIdx.x * 256 + threadIdx.x;
    int y = p >> 8, x = p & 255;
    __shared__ float xv[101];
    __shared__ int sh[102];
    __shared__ float redm[256];
    if (threadIdx.x < 101) xv[threadIdx.x] = xv_val(threadIdx.x);
    if (threadIdx.x < 102) sh[threadIdx.x] = 0;
    __syncthreads();
    const float* src = ia + (((size_t)b) << 16);
    float a1 = gdmw[0] * 4.f;
    auto rd = [&](int dy, int dx) -> float {
        int iy = y + dy, ix = x + dx;
        if ((unsigned)iy >= 256u || (unsigned)ix >= 256u) return 0.f;
        return src[iy * 256 + ix];
    };
    float acc = rd(0, 0)
        - 0.125f  * (rd(-1, 0) + rd(0, -1) + rd(0, 1) + rd(1, 0))
        - 0.0625f * (rd(-2, 0) + rd(-1, -1) + rd(-1, 1) + rd(0, -2) +
                     rd(0, 2) + rd(1, -1) + rd(1, 1) + rd(2, 0));
    float raw = fabsf(a1 * acc);
    float val = (raw < 1e-6f) ? 0.f : raw;
    xgl[(((size_t)b) << 16) + p] = val;
    if (val > 0.f) {
        int lo = 0, hi = 101;
        while (lo < hi) { int mid = (lo + hi) >> 1; if (val <= xv[mid]) hi = mid; else lo = mid + 1; }
        atomicAdd(&sh[lo], 1);
    }
    redm[threadIdx.x] = val; __syncthreads();
    for (int off = 128; off > 0; off >>= 1) {
        if (threadIdx.x < off) redm[threadIdx.x] = fmaxf(redm[threadIdx.x], redm[threadIdx.x + off]);
        __syncthreads();
    }
    if (threadIdx.x == 0) atomicMax(&xmax[b], __float_as_uint(redm[0]));
    if (threadIdx.x < 102 && sh[threadIdx.x]) atomicAdd(&hist[b * 102 + threadIdx.x], sh[threadIdx.x]);
}

// ---- G5: weight_att (BN affine on mean), sort params, argmin over cumulative pct ----
__global__ void k_thresholds(const float* __restrict__ ysum, const float* __restrict__ gamma,
                             const float* __restrict__ beta, const float* __restrict__ mean,
                             const float* __restrict__ var, const int* __restrict__ hist,
                             float* __restrict__ thr) {
    int b = threadIdx.x;
    if (b >= 8) return;
    float wa[5];
    for (int c = 1; c < 5; ++c) {
        float m = ysum[b * 5 + c] * (1.f / 16384.f);
        wa[c] = tanhf((m - mean[c]) * rsqrtf(var[c] + 1e-5f) * gamma[c] + beta[c]);
    }
    float pr[4] = {0.2f + 0.05f * wa[1], 0.4f + 0.05f * wa[2],
                   0.6f + 0.05f * wa[3], 0.8f + 0.05f * wa[4]};
    auto sw = [&](int i, int j) { if (pr[i] > pr[j]) { float t = pr[i]; pr[i] = pr[j]; pr[j] = t; } };
    sw(0, 1); sw(2, 3); sw(0, 2); sw(1, 3); sw(1, 2);
    int all = 0;
    for (int i = 0; i <= 101; ++i) all += hist[b * 102 + i];
    float bestz[4] = {1e30f, 1e30f, 1e30f, 1e30f};
    int besti[4] = {0, 0, 0, 0};
    int cum = 0;
    for (int i = 0; i <= 100; ++i) {
        cum += hist[b * 102 + i];
        float pct = (float)cum / (float)all;
        for (int t = 0; t < 4; ++t) {
            float z = fabsf(pct - pr[t]);
            if (z < bestz[t]) { bestz[t] = z; besti[t] = i; }
        }
    }
    for (int t = 0; t < 4; ++t) thr[b * 4 + t] = xv_val(besti[t]);
}

// ---- fused (optional mask) + h-box9 + v-box9, stride-1, 8 output rows / block ----
#define F1_STR 268
template<bool MASK>
__global__ __launch_bounds__(256) void k_hv(const float* __restrict__ in,
                                            const float* __restrict__ thr,
                                            const unsigned* __restrict__ xmax,
                                            float* __restrict__ outp) {
    int plane = blockIdx.y;          // 0..39
    int r0 = blockIdx.x * 8;         // output rows r0..r0+7
    float tmin = 0.f, tmax = 0.f;
    const float* src;
    if (MASK) {
        int b = plane / 5, band = plane - 5 * b;
        tmin = (band == 0) ? 0.f : thr[b * 4 + band - 1];
        tmax = (band == 4) ? __uint_as_float(xmax[b]) : thr[b * 4 + band];
        src = in + (((size_t)b) << 16);
    } else {
        src = in + (((size_t)plane) << 16);
    }
    __shared__ float mr[16][F1_STR];
    __shared__ float hh[16][256];
    int tid = threadIdx.x;
    // load 16 rows (r0-4 .. r0+11), store at col+4; pads zeroed
    for (int l = tid; l < 16 * 256; l += 256) {
        int i = l >> 8, c = l & 255;
        int rr = r0 - 4 + i;
        float v = ((unsigned)rr < 256u) ? src[rr * 256 + c] : 0.f;
        if (MASK) v = (v > tmin && v <= tmax) ? 1.f : 0.f;
        mr[i][c + 4] = v;
    }
    if (tid < 128) { int i = tid >> 3, p = tid & 7; mr[i][p < 4 ? p : 256 + p] = 0.f; }
    __syncthreads();
    // h-box: thread owns row r=tid>>4, cols x0..x0+15; rolling sum
    {
        int r = tid >> 4, x0 = (tid & 15) * 16;
        float w[24];
#pragma unroll
        for (int k = 0; k < 6; ++k) {
            float4 q = *(const float4*)&mr[r][x0 + 4 * k];
            w[4 * k] = q.x; w[4 * k + 1] = q.y; w[4 * k + 2] = q.z; w[4 * k + 3] = q.w;
        }
        float o[16];
        float s = 0.f;
#pragma unroll
        for (int k = 0; k < 9; ++k) s += w[k];
#pragma unroll
        for (int j = 0; j < 16; ++j) {
            o[j] = s * (1.f / 9.f);
            if (j < 15) s += w[j + 9] - w[j];
        }
#pragma unroll
        for (int k = 0; k < 4; ++k) {
            float4 q = {o[4 * k], o[4 * k + 1], o[4 * k + 2], o[4 * k + 3]};
            *(float4*)&hh[r][x0 + 4 * k] = q;
        }
    }
    __syncthreads();
    // v-box: thread = column; rolling sum over 16 h-rows -> 8 outputs
    {
        int c = tid;
        float ld[16];
#pragma unroll
        for (int i = 0; i < 16; ++i) ld[i] = hh[i][c];
        float s = 0.f;
#pragma unroll
        for (int k = 0; k < 9; ++k) s += ld[k];
        float* dst = outp + (((size_t)plane) << 16);
#pragma unroll
        for (int j = 0; j < 8; ++j) {
            dst[(r0 + j) * 256 + c] = s * (1.f / 9.f);
            if (j < 7) s += ld[j + 9] - ld[j];
        }
    }
}

// ---- fused h-box9(s2) + v-box9(s2) + per-plane min/max atomics: [40][256][256]->[40][128][128] ----
#define F3_STR 264
__global__ __launch_bounds__(256) void k_hv_s2(const float* __restrict__ in,
                                               float* __restrict__ outp,
                                               unsigned* __restrict__ mnb,
                                               unsigned* __restrict__ mxb) {
    int plane = blockIdx.y;
    int r0 = blockIdx.x * 8;   // output rows (of 128)
    __shared__ float mr[24][F3_STR];
    __shared__ float hh[24][128];
    int tid = threadIdx.x;
    const float* src = in + (((size_t)plane) << 16);
    for (int l = tid; l < 24 * 256; l += 256) {
        int i = l >> 8, c = l & 255;
        int rr = 2 * r0 - 4 + i;
        mr[i][c + 4] = ((unsigned)rr < 256u) ? src[rr * 256 + c] : 0.f;
    }
    if (tid < 192) { int i = tid >> 3, p = tid & 7; mr[i][p < 4 ? p : 256 + p] = 0.f; }
    __syncthreads();
    // h-box stride2: hh[i][ox] over 24 rows x 128 cols
    for (int l = tid; l < 24 * 128; l += 256) {
        int i = l >> 7, ox = l & 127;
        float s = 0.f;
#pragma unroll
        for (int k = 0; k < 9; ++k) s += mr[i][2 * ox + k];
        hh[i][ox] = s * (1.f / 9.f);
    }
    __syncthreads();
    // v-box stride2 + minmax
    float vmn = 1e30f, vmx = -1e30f;
    {
        int c = tid & 127, jh = tid >> 7;
        float* dst = outp + (size_t)plane * 16384;
#pragma unroll
        for (int q = 0; q < 4; ++q) {
            int j = jh * 4 + q;
            float s = 0.f;
#pragma unroll
            for (int k = 0; k < 9; ++k) s += hh[2 * j + k][c];
            s *= (1.f / 9.f);
            dst[(r0 + j) * 128 + c] = s;
            vmn = fminf(vmn, s); vmx = fmaxf(vmx, s);
        }
    }
    __shared__ float smn[256], smx[256];
    smn[tid] = vmn; smx[tid] = vmx; __syncthreads();
    for (int off = 128; off > 0; off >>= 1) {
        if (tid < off) {
            smn[tid] = fminf(smn[tid], smn[tid + off]);
            smx[tid] = fmaxf(smx[tid], smx[tid + off]);
        }
        __syncthreads();
    }
    if (tid == 0) {
        atomicMin(&mnb[plane], __float_as_uint(smn[0]));
        atomicMax(&mxb[plane], __float_as_uint(smx[0]));
    }
}

// ---- normalize ----
__global__ __launch_bounds__(256) void k_norm(const float* __restrict__ in,
                                              const unsigned* __restrict__ mnb,
                                              const unsigned* __restrict__ mxb,
                                              float* __restrict__ outp) {
    int i4 = blockIdx.x * 256 + threadIdx.x;      // 163840
    int idx = i4 * 4;
    int plane = idx >> 14;
    float mn = __uint_as_float(mnb[plane]), mx = __uint_as_float(mxb[plane]);
    float inv = 1.f / (mx - mn);
    float4 v = *(const float4*)&in[idx];
    float4 o = {(v.x - mn) * inv, (v.y - mn) * inv, (v.z - mn) * inv, (v.w - mn) * inv};
    *(float4*)&outp[idx] = o;
}

// ---- H1: A_d[o][c] = sum_m fc_w[o][d*64+m] * g_d[m][c]; stored At[(d*64+c)*64+o] (scale folded) ----
__global__ __launch_bounds__(256) void k_mixA(const float* __restrict__ hw,
                                              const float* __restrict__ fcw,
                                              float* __restrict__ At) {
    int idx = blockIdx.x * 256 + threadIdx.x;  // 320*64
    int o = idx & 63; int k = idx >> 6;
    int d = k >> 6; int c = k & 63;
    const int goff[5] = {0, 1, 2, 3, 8};
    float scale = (d == 4) ? 4.f : 1.f;
    int off = goff[d];
    float s = 0.f;
    for (int m = 0; m < 64; ++m)
        s += fcw[o * 320 + d * 64 + m] * hw[(m * 64 + c) * 9 + off];
    At[k * 64 + o] = s * scale;
}

// ---- H2: fused depthwise stencils + channel-mix, pipelined (2 ch/iter, prefetch, dbuf tl/al) ----
__global__ __launch_bounds__(256) void k_hge(const float* __restrict__ feat,
                                             const float* __restrict__ At,
                                             const float* __restrict__ fcb,
                                             float* __restrict__ out) {
    int tile = blockIdx.x; int b = blockIdx.y;
    int ty = (tile >> 3) * 16, tx = (tile & 7) * 16;
    __shared__ float ft[2][20][21];          // [ch][row][col] (single buffer)
    __shared__ float tl[2][2][5][256];       // [buf][ch][dir][px]
    __shared__ float al[2][2][5][64];        // [buf][ch][dir][o]
    int tid = threadIdx.x;
    int og = tid >> 5, pg = tid & 31;
    float acc[8][8];                         // [px j][out oi]
#pragma unroll
    for (int i = 0; i < 8; ++i)
#pragma unroll
        for (int j = 0; j < 8; ++j) acc[i][j] = 0.f;

    // precompute per-j load descriptors (element l = tid + 256*j of the 1440-pack)
    const float* cur[6];
    int str[6];
    bool ok[6];
#pragma unroll
    for (int j = 0; j < 6; ++j) {
        int l = tid + 256 * j;
        cur[j] = nullptr; str[j] = 0; ok[j] = false;
        if (l < 800) {
            int ch = (l >= 400); int rem = l - ch * 400;
            int r = rem / 20, cx = rem - r * 20;
            int gy = ty - 2 + r, gx = tx - 2 + cx;
            if ((unsigned)gy < 128u && (unsigned)gx < 128u) {
                cur[j] = feat + (((size_t)(b * 64 + ch)) << 14) + gy * 128 + gx;
                str[j] = 2 << 14;  // advance 2 channels
                ok[j] = true;
            }
        } else if (l < 1440) {
            int q = l - 800;
            int ch = (q >= 320); int k = q - ch * 320;   // d*64+o
            cur[j] = At + ((((k >> 6) * 64) + ch) << 6) + (k & 63);
            str[j] = 128;  // advance 2 channels: (d*64+c) stride 64 per channel * 64 o
            ok[j] = true;
        }
    }

    float pr[6];
#pragma unroll
    for (int j = 0; j < 6; ++j) pr[j] = ok[j] ? *cur[j] : 0.f;

    int py = tid >> 4, px = tid & 15;
    for (int g = 0; g < 32; ++g) {
        int buf = g & 1;
        // write prefetched pair into LDS (ft single-buffered is safe: stencil(g-1)
        // readers all passed the pre-FMA barrier of iter g-1)
#pragma unroll
        for (int j = 0; j < 6; ++j) {
            int l = tid + 256 * j;
            if (l < 800) {
                int ch = (l >= 400); int rem = l - ch * 400;
                int r = rem / 20, cx = rem - r * 20;
                ft[ch][r][cx] = pr[j];
            } else if (l < 1440) {
                ((float*)al[buf])[l - 800] = pr[j];
            }
        }
        __syncthreads();
        // issue prefetch for next pair (hidden under stencil + FMA)
        if (g < 31) {
#pragma unroll
            for (int j = 0; j < 6; ++j) {
                if (ok[j]) { cur[j] += str[j]; pr[j] = *cur[j]; }
            }
        }
        // stencils: thread owns pixel tid
        {
            int cy = py + 2, cx = px + 2;
#pragma unroll
            for (int ch = 0; ch < 2; ++ch) {
                float fm2 = ft[ch][cy - 2][cx], f2p = ft[ch][cy + 2][cx];
                float fl2 = ft[ch][cy][cx - 2], fr2 = ft[ch][cy][cx + 2];
                float a  = ft[ch][cy - 1][cx - 1], bq = ft[ch][cy - 1][cx], cc = ft[ch][cy - 1][cx + 1];
                float dd = ft[ch][cy][cx - 1],     ee = ft[ch][cy][cx],     ffv = ft[ch][cy][cx + 1];
                float g_ = ft[ch][cy + 1][cx - 1], h  = ft[ch][cy + 1][cx], i2 = ft[ch][cy + 1][cx + 1];
                tl[buf][ch][0][tid] = (a + 2.f * bq + cc) - (g_ + 2.f * h + i2);
                tl[buf][ch][1][tid] = 2.f * a + bq + dd - ffv - h - 2.f * i2;
                tl[buf][ch][2][tid] = (a - cc) + 2.f * (dd - ffv) + (g_ - i2);
                tl[buf][ch][3][tid] = -bq - 2.f * cc + dd - ffv + 2.f * g_ + h;
                tl[buf][ch][4][tid] = ee - 0.125f * (bq + dd + ffv + h)
                                    - 0.0625f * (fm2 + a + cc + fl2 + fr2 + g_ + i2 + f2p);
            }
        }
        __syncthreads();
        // FMA: 8 px (pg*8..+7) x 8 outs (og*8..+7), b128 LDS reads
#pragma unroll
        for (int ch = 0; ch < 2; ++ch) {
#pragma unroll
            for (int d = 0; d < 5; ++d) {
                float4 a0 = *(const float4*)&al[buf][ch][d][og * 8];
                float4 a1 = *(const float4*)&al[buf][ch][d][og * 8 + 4];
                float4 t0 = *(const float4*)&tl[buf][ch][d][pg * 8];
                float4 t1 = *(const float4*)&tl[buf][ch][d][pg * 8 + 4];
                float av[8] = {a0.x, a0.y, a0.z, a0.w, a1.x, a1.y, a1.z, a1.w};
                float tv[8] = {t0.x, t0.y, t0.z, t0.w, t1.x, t1.y, t1.z, t1.w};
#pragma unroll
                for (int j = 0; j < 8; ++j)
#pragma unroll
                    for (int oi = 0; oi < 8; ++oi)
                        acc[j][oi] = fmaf(av[oi], tv[j], acc[j][oi]);
            }
        }
    }
    // write-out: thread's 8 px are row pg>>1, cols (pg&1)*8..+7
    int yy = ty + (pg >> 1), xx = tx + (pg & 1) * 8;
#pragma unroll
    for (int oi = 0; oi < 8; ++oi) {
        int o = og * 8 + oi;
        float bias = fcb[o];
        float4 v0 = {acc[0][oi] + bias, acc[1][oi] + bias, acc[2][oi] + bias, acc[3][oi] + bias};
        float4 v1 = {acc[4][oi] + bias, acc[5][oi] + bias, acc[6][oi] + bias, acc[7][oi] + bias};
        float* dst = out + (((size_t)(b * 64 + o)) << 14) + yy * 128 + xx;
        *(float4*)dst = v0;
        *(float4*)(dst + 4) = v1;
    }
}

extern "C" void kernel_launch(void* const* d_in, const int* in_sizes, int n_in,
                              void* d_out, int out_size, void* d_ws, size_t ws_size,
                              hipStream_t stream) {
    const float* x    = (const float*)d_in[0];
    const float* gdmw = (const float*)d_in[1];
    const float* convw= (const float*)d_in[2];
    const float* bng  = (const float*)d_in[3];
    const float* bnb  = (const float*)d_in[4];
    const float* bnm  = (const float*)d_in[5];
    const float* bnv  = (const float*)d_in[6];
    const float* feat = (const float*)d_in[7];
    const float* hw   = (const float*)d_in[8];
    const float* fcw  = (const float*)d_in[9];
    const float* fcb  = (const float*)d_in[10];
    float* out = (float*)d_out;
    float* ws  = (float*)d_ws;

    float* At   = ws + WS_AT;
    float* ysum = ws + WS_YSUM;
    unsigned* xmax = (unsigned*)(ws + WS_XMAX);
    int* hist   = (int*)(ws + WS_HIST);
    float* thr  = ws + WS_THR;
    unsigned* mnb = (unsigned*)(ws + WS_MN);
    unsigned* mxb = (unsigned*)(ws + WS_MX);
    float* xp   = ws + WS_XP;
    float* ia   = ws + WS_IA;
    float* xgl  = ws + WS_XGL;

    // pool ping-pong buffers live in the hge half of d_out (hge written last)
    float* hge = out + GDM_OUT;
    float* p0  = hge;                  // [40][256][256]
    float* p1  = hge + 2621440;        // [40][256][256]
    float* p2  = hge + 5242880;        // [40][128][128]

    hipMemsetAsync(ws + WS_YSUM, 0, (WS_THR - WS_YSUM) * sizeof(float), stream);
    hipMemsetAsync(ws + WS_MN, 0xFF, 40 * sizeof(unsigned), stream);
    hipMemsetAsync(ws + WS_MX, 0x00, 40 * sizeof(unsigned), stream);

    k_pool3_mean  <<<2048, 256, 0, stream>>>(x, xp, ia);
    k_conv7_reduce<<<dim3(64, 5, 8), 256, 0, stream>>>(xp, convw, ysum);
    k_gl_hist     <<<dim3(256, 8), 256, 0, stream>>>(ia, gdmw, xgl, hist, xmax);
    k_thresholds  <<<1, 64, 0, stream>>>(ysum, bng, bnb, bnm, bnv, hist, thr);
    k_hv<true>    <<<dim3(32, 40), 256, 0, stream>>>(xgl, thr, xmax, p0);
    k_hv<false>   <<<dim3(32, 40), 256, 0, stream>>>(p0, nullptr, nullptr, p1);
    k_hv_s2       <<<dim3(16, 40), 256, 0, stream>>>(p1, p2, mnb, mxb);
    k_norm        <<<640, 256, 0, stream>>>(p2, mnb, mxb, out);

    k_mixA        <<<80, 256, 0, stream>>>(hw, fcw, At);
    k_hge         <<<dim3(64, 8), 256, 0, stream>>>(feat, At, fcb, out + GDM_OUT);
}